// Round 12
// baseline (1021.840 us; speedup 1.0000x reference)
//
#include <hip/hip_runtime.h>
#include <hip/hip_fp16.h>

#define NN 50000
#define EE 800000
#define DIM 128
#define OUTC 20
#define LL 7
#define LE (LL*EE)
#define LN (LL*NN)
#define BN_EPS 1e-5f
#define LSTRIDE 136     // bf16 elems per LDS row
#define NREP 64         // BN stat replicas
#define NBUK 196        // coarse buckets of 256 dsts per layer
#define GMS  200        // padded Gm stride
#define NBLK 128        // edge-blocks per layer (EE/NBLK = 6250)
#define CH   6250
#define SCN  (LL*NBUK*NBLK)   // 175616 scan entries

typedef __attribute__((ext_vector_type(8))) short short8;
typedef __attribute__((ext_vector_type(4))) float f32x4;

static __device__ __forceinline__ float sigm(float z){ return 1.0f/(1.0f+expf(-z)); }
static __device__ __forceinline__ unsigned short f2bf(float f){
  unsigned int u = __float_as_uint(f);
  u += 0x7FFF + ((u>>16)&1);            // RNE
  return (unsigned short)(u>>16);
}
static __device__ __forceinline__ float bf2f(unsigned short s){
  return __uint_as_float(((unsigned int)s)<<16);
}

// ======== preprocessing: counting sort, all atomics in LDS, streaming writes ========
// buckets of 256 dsts -> avg run 32 edges = 128B btmpP: full-line streaming writes

// P1: per-(layer,block) LDS histogram over 196 coarse buckets
__global__ __launch_bounds__(256) void k_bh(const int* __restrict__ ei,
    int* __restrict__ Gm){
  int l = blockIdx.x >> 7, b = blockIdx.x & 127;
  int t = threadIdx.x;
  __shared__ int h[NBUK];
  if (t<NBUK) h[t]=0;
  __syncthreads();
  const int* dsts = ei + (size_t)(2*l+1)*EE + b*CH;
  for (int k=t; k<CH; k+=256) atomicAdd(&h[__builtin_nontemporal_load(dsts+k)>>8], 1);
  __syncthreads();
  int* g = Gm + (size_t)(l*NBLK+b)*GMS;
  if (t<NBUK) g[t]=h[t];
}

// P2: exclusive scan over (l,buk,b) enumeration of Gm[(l,b),buk]
__global__ __launch_bounds__(256) void k_scan1p(const int* __restrict__ Gm,
    int* __restrict__ part, int* __restrict__ bsums){
  __shared__ int s[256];
  int t = threadIdx.x;
  int base = blockIdx.x*4096 + t*16;
  int v[16]; int sum = 0;
  #pragma unroll
  for (int i=0;i<16;i++){
    int idx = base+i; int val = 0;
    if (idx < SCN){
      int l = idx/(NBUK*NBLK);
      int r = idx - l*(NBUK*NBLK);
      int buk = r>>7, b = r&127;
      val = Gm[(size_t)(l*NBLK+b)*GMS + buk];
    }
    v[i]=val; sum+=val;
  }
  s[t]=sum; __syncthreads();
  for (int off=1; off<256; off<<=1){
    int x = (t>=off)? s[t-off] : 0;
    __syncthreads(); s[t]+=x; __syncthreads();
  }
  if (t==255) bsums[blockIdx.x] = s[255];
  int run = s[t]-sum;
  #pragma unroll
  for (int i=0;i<16;i++){ if (base+i<SCN) part[base+i]=run; run += v[i]; }
}

__global__ __launch_bounds__(1024) void k_scan2(int* bsums, int nb){
  __shared__ int s[1024];
  int t=threadIdx.x;
  int v = (t<nb)? bsums[t]:0;
  s[t]=v; __syncthreads();
  for (int off=1; off<1024; off<<=1){
    int x=(t>=off)? s[t-off]:0; __syncthreads(); s[t]+=x; __syncthreads();
  }
  if (t<nb) bsums[t] = s[t]-v;
}

__global__ void k_scan3(int* __restrict__ S, const int* __restrict__ bsums){
  int gid = blockIdx.x*256+threadIdx.x;
  if (gid < SCN) S[gid] += bsums[gid>>12];
  if (gid==0) S[SCN]=LE;
}

// P3: LDS counting-sort by bucket (record = origk|dlow8|buk), contiguous run writes
__global__ __launch_bounds__(256) void k_bscatter(const int* __restrict__ ei,
    const float* __restrict__ ew, const int* __restrict__ S,
    unsigned int* __restrict__ btmpP, unsigned char* __restrict__ btmpD){
  int l = blockIdx.x >> 7, b = blockIdx.x & 127;
  int t = threadIdx.x;
  __shared__ int cnt[NBUK], bstart[NBUK], cur[NBUK], runb[NBUK];
  __shared__ int ps[256];
  __shared__ unsigned int eb[CH];       // 25 KB
  if (t<NBUK) cnt[t]=0;
  __syncthreads();
  const int* srcs = ei + (size_t)(2*l)*EE + b*CH;
  const int* dsts = ei + (size_t)(2*l+1)*EE + b*CH;
  const float* wsrc = ew + (size_t)l*EE + b*CH;
  for (int k=t;k<CH;k+=256) atomicAdd(&cnt[dsts[k]>>8],1);
  __syncthreads();
  // exclusive scan over 196 counts (1 per thread)
  int v = (t<NBUK)? cnt[t]:0;
  ps[t]=v; __syncthreads();
  for (int o=1;o<256;o<<=1){ int x=(t>=o)?ps[t-o]:0; __syncthreads(); ps[t]+=x; __syncthreads(); }
  if (t<NBUK){ bstart[t]=ps[t]-v; cur[t]=ps[t]-v; runb[t] = S[(size_t)(l*NBUK+t)*NBLK + b]; }
  __syncthreads();
  // place records into LDS in bucket order (L1 re-read of dsts)
  for (int k=t;k<CH;k+=256){
    int dst = dsts[k];
    int buk = dst>>8;
    int pos = atomicAdd(&cur[buk],1);
    eb[pos] = (unsigned)k | ((unsigned)(dst&255)<<13) | ((unsigned)buk<<21);
  }
  __syncthreads();
  // streaming write: each bucket run contiguous in LDS and global (avg 128B)
  for (int k=t;k<CH;k+=256){
    unsigned e = eb[k];
    int buk = e>>21;
    int origk = e & 0x1FFF;
    int src = srcs[origk];
    float w = wsrc[origk];
    int gp = runb[buk] + (k - bstart[buk]);
    unsigned short hw = __half_as_ushort(__float2half(w));
    btmpP[gp] = (unsigned)src | ((unsigned)hw<<16);
    btmpD[gp] = (unsigned char)((e>>13)&255);
  }
}

// P4: per-bucket (256 dsts) count+scan from 1B dst array, direct scatter of packed edges
__global__ __launch_bounds__(256) void k_fsort(const unsigned int* __restrict__ btmpP,
    const unsigned char* __restrict__ btmpD, const int* __restrict__ S,
    unsigned int* __restrict__ sedge, int* __restrict__ offs){
  int lbuk = blockIdx.x;                 // 0..1371
  int l = lbuk/NBUK, bl = lbuk - l*NBUK;
  int t = threadIdx.x;
  int base = S[(size_t)lbuk*NBLK];
  int end  = S[(size_t)(lbuk+1)*NBLK];
  int nE = end - base;
  __shared__ int cnt[256], sc[256];
  cnt[t]=0;
  __syncthreads();
  for (int k=t; k<nE; k+=256) atomicAdd(&cnt[btmpD[base+k]], 1);
  __syncthreads();
  int c = cnt[t];
  sc[t]=c;
  __syncthreads();
  for (int o=1;o<256;o<<=1){
    int v = (t>=o)? sc[t-o]:0;
    __syncthreads();
    sc[t]+=v;
    __syncthreads();
  }
  {
    int excl = sc[t]-c;
    int node = bl*256+t;
    if (node<NN) offs[(size_t)l*NN+node] = base + excl;
    cnt[t] = base + excl;                // becomes cursor
  }
  if (lbuk==0 && t==255) offs[LN]=LE;
  __syncthreads();
  for (int k=t; k<nE; k+=256){
    int d = btmpD[base+k];
    int r = atomicAdd(&cnt[d],1);
    sedge[r] = btmpP[base+k];
  }
}

// gather embedding -> bf16 x
__global__ void k_gather_emb(const int* __restrict__ verts, const float* __restrict__ emb,
                             unsigned short* __restrict__ x){
  int gid = blockIdx.x*256+threadIdx.x;   // NN*16 groups of 8
  int n = gid>>4, q = gid&15;
  if (n>=NN) return;
  int v = verts[n];
  const float4* p = (const float4*)emb + (size_t)v*32 + q*2;
  float4 v0 = p[0], v1 = p[1];
  short8 w;
  w[0]=(short)f2bf(v0.x); w[1]=(short)f2bf(v0.y); w[2]=(short)f2bf(v0.z); w[3]=(short)f2bf(v0.w);
  w[4]=(short)f2bf(v1.x); w[5]=(short)f2bf(v1.y); w[6]=(short)f2bf(v1.z); w[7]=(short)f2bf(v1.w);
  *(short8*)(x + (size_t)n*128 + q*8) = w;
}

// ---- transpose + bf16-convert all 18 hidden weight matrices: Wt[m][n][k] ----
__global__ __launch_bounds__(256) void k_prep_w(const float* __restrict__ wh,
    const float* __restrict__ tewl, const float* __restrict__ tewc,
    unsigned short* __restrict__ Wt){
  int gid = blockIdx.x*256+threadIdx.x;          // 18*16384
  int m = gid>>14; int idx = gid&16383;
  int n = idx>>7, k = idx&127;
  const float* src = (m<6)? wh + (size_t)m*16384
                   : (m<12)? tewl + (size_t)(m-6)*16384
                   : tewc + (size_t)(m-12)*16384;
  Wt[gid] = f2bf(src[k*128+n]);
}

// stage 64 bf16 rows -> LDS tile [64][LSTRIDE]
static __device__ __forceinline__ void stage64bf(const unsigned short* __restrict__ src,
    int row0, int M, unsigned short* Xs, int tid){
  #pragma unroll
  for (int it=0; it<4; it++){
    int idx = tid + it*256;
    int r = idx>>4, k8 = idx&15;
    short8 v = short8(0);
    if (row0+r < M) v = *(const short8*)(src + (size_t)(row0+r)*128 + k8*8);
    *(short8*)&Xs[r*LSTRIDE + k8*8] = v;
  }
}

// ---------------- MFMA GEMM: Ybf16 = xbf @ Wt (layer 0 only) ----------------
__global__ __launch_bounds__(256) void k_gemm_sup(const unsigned short* __restrict__ X,
    const unsigned short* __restrict__ Wt, unsigned short* __restrict__ Y, int M){
  __shared__ unsigned short Xs[64*LSTRIDE];
  int tid = threadIdx.x;
  int row0 = blockIdx.x*64;
  stage64bf(X, row0, M, Xs, tid);
  __syncthreads();
  int w = tid>>6, lane = tid&63, m = lane&15, q = lane>>4;
  f32x4 acc[8];
  #pragma unroll
  for (int nt=0;nt<8;nt++){ acc[nt][0]=0.f; acc[nt][1]=0.f; acc[nt][2]=0.f; acc[nt][3]=0.f; }
  #pragma unroll
  for (int kc=0; kc<4; kc++){
    short8 a = *(const short8*)&Xs[(16*w+m)*LSTRIDE + kc*32 + 8*q];
    #pragma unroll
    for (int nt=0; nt<8; nt++){
      short8 b = *(const short8*)&Wt[(size_t)(nt*16+m)*128 + kc*32 + 8*q];
      acc[nt] = __builtin_amdgcn_mfma_f32_16x16x32_bf16(a, b, acc[nt], 0,0,0);
    }
  }
  #pragma unroll
  for (int nt=0; nt<8; nt++){
    #pragma unroll
    for (int i=0;i<4;i++){
      int rr = row0 + 16*w + 4*q + i;
      if (rr<M) Y[(size_t)rr*128 + nt*16 + m] = f2bf(acc[nt][i]);
    }
  }
}

// ------- fused: BN(bf16 h)+ReLU -> LDS; dual MFMA; gate; short8 writeback; [+ next sup] -------
template<int FUSE>
__global__ __launch_bounds__(256) void k_gemm_gate2(const unsigned short* __restrict__ H,
    const float* __restrict__ stL,            // NREP replicas [rep][sum128|sq128]
    const float* __restrict__ gamma, const float* __restrict__ beta,
    const unsigned short* __restrict__ Wl, const unsigned short* __restrict__ Wc,
    const unsigned short* __restrict__ Wn, const float* __restrict__ teb,
    unsigned short* __restrict__ x, unsigned short* __restrict__ supY, int M){
  __shared__ unsigned short XsX[64*LSTRIDE];
  __shared__ unsigned short XsH[64*LSTRIDE];
  __shared__ float sSc[128], sOff[128];
  int tid = threadIdx.x;
  int row0 = blockIdx.x*64;
  if (tid<128){
    float s=0.f, sq=0.f;
    #pragma unroll 8
    for (int g=0; g<NREP; g++){ s += stL[g*256+tid]; sq += stL[g*256+128+tid]; }
    float mean = s*(1.0f/NN);
    float var = sq*(1.0f/NN) - mean*mean;
    float sc = rsqrtf(var+BN_EPS)*gamma[tid];
    sSc[tid]=sc; sOff[tid]=beta[tid]-mean*sc;
  }
  stage64bf(x, row0, M, XsX, tid);
  __syncthreads();
  #pragma unroll
  for (int it=0; it<4; it++){
    int idx = tid + it*256;
    int r = idx>>4, k8 = idx&15;
    short8 hv8 = short8(0);
    if (row0+r < M) hv8 = *(const short8*)(H + (size_t)(row0+r)*128 + k8*8);
    int k = k8*8;
    short8 w;
    #pragma unroll
    for (int j=0;j<8;j++){
      float o = bf2f((unsigned short)hv8[j]);
      float hn = fmaxf(fmaf(o, sSc[k+j], sOff[k+j]), 0.f);
      w[j] = (short)f2bf(hn);
    }
    *(short8*)&XsH[r*LSTRIDE + k8*8] = w;
  }
  __syncthreads();
  int w = tid>>6, lane = tid&63, m = lane&15, q = lane>>4;
  f32x4 acc[8];
  #pragma unroll
  for (int nt=0;nt<8;nt++){ acc[nt][0]=0.f; acc[nt][1]=0.f; acc[nt][2]=0.f; acc[nt][3]=0.f; }
  #pragma unroll
  for (int kc=0; kc<4; kc++){
    short8 a = *(const short8*)&XsX[(16*w+m)*LSTRIDE + kc*32 + 8*q];
    #pragma unroll
    for (int nt=0; nt<8; nt++){
      short8 b = *(const short8*)&Wl[(size_t)(nt*16+m)*128 + kc*32 + 8*q];
      acc[nt] = __builtin_amdgcn_mfma_f32_16x16x32_bf16(a, b, acc[nt], 0,0,0);
    }
  }
  #pragma unroll
  for (int kc=0; kc<4; kc++){
    short8 a = *(const short8*)&XsH[(16*w+m)*LSTRIDE + kc*32 + 8*q];
    #pragma unroll
    for (int nt=0; nt<8; nt++){
      short8 b = *(const short8*)&Wc[(size_t)(nt*16+m)*128 + kc*32 + 8*q];
      acc[nt] = __builtin_amdgcn_mfma_f32_16x16x32_bf16(a, b, acc[nt], 0,0,0);
    }
  }
  // gate epilogue: write xn into XsH (each cell owned by one thread), XsX too if FUSE
  #pragma unroll
  for (int nt=0; nt<8; nt++){
    int col = nt*16 + m;
    float bias = teb[col];
    #pragma unroll
    for (int i=0;i<4;i++){
      int lr = 16*w + 4*q + i;
      float hv = bf2f(XsH[lr*LSTRIDE + col]);
      float xo = bf2f(XsX[lr*LSTRIDE + col]);
      float g = sigm(acc[nt][i] + bias);
      unsigned short xnb = f2bf(g*hv + (1.f-g)*xo);
      XsH[lr*LSTRIDE + col] = xnb;
      if (FUSE) XsX[lr*LSTRIDE + col] = xnb;
    }
  }
  __syncthreads();
  // coalesced short8 writeback of x_new
  #pragma unroll
  for (int it=0; it<4; it++){
    int idx = tid + it*256;
    int r = idx>>4, k8 = idx&15;
    if (row0+r < M)
      *(short8*)(x + (size_t)(row0+r)*128 + k8*8) = *(short8*)&XsH[r*LSTRIDE + k8*8];
  }
  if (FUSE){
    #pragma unroll
    for (int nt=0;nt<8;nt++){ acc[nt][0]=0.f; acc[nt][1]=0.f; acc[nt][2]=0.f; acc[nt][3]=0.f; }
    #pragma unroll
    for (int kc=0; kc<4; kc++){
      short8 a = *(const short8*)&XsX[(16*w+m)*LSTRIDE + kc*32 + 8*q];
      #pragma unroll
      for (int nt=0; nt<8; nt++){
        short8 b = *(const short8*)&Wn[(size_t)(nt*16+m)*128 + kc*32 + 8*q];
        acc[nt] = __builtin_amdgcn_mfma_f32_16x16x32_bf16(a, b, acc[nt], 0,0,0);
      }
    }
    #pragma unroll
    for (int nt=0; nt<8; nt++){
      #pragma unroll
      for (int i=0;i<4;i++){
        int rr = row0 + 16*w + 4*q + i;
        if (rr<M) supY[(size_t)rr*128 + nt*16 + m] = f2bf(acc[nt][i]);
      }
    }
  }
}

// ---------------- Y[M,20] = bf16 X[M,128] @ W[128,20] (fp32 acc) ----------------
__global__ __launch_bounds__(256) void k_gemm_out(const unsigned short* __restrict__ X,
    const float* __restrict__ W, float* __restrict__ Y, int M){
  __shared__ float Ws[DIM*OUTC];
  __shared__ float Xs2[8*DIM];
  int tid=threadIdx.x;
  for (int i=tid;i<DIM*OUTC;i+=256) Ws[i]=W[i];
  int row0=blockIdx.x*8;
  if (tid<128){
    int r = tid>>4, k8 = tid&15;
    short8 v = short8(0);
    if (row0+r<M) v = *(const short8*)(X + (size_t)(row0+r)*128 + k8*8);
    #pragma unroll
    for (int j=0;j<8;j++) Xs2[r*DIM+k8*8+j] = bf2f((unsigned short)v[j]);
  }
  __syncthreads();
  int c = tid&31, rl=tid>>5;
  if (c<OUTC && row0+rl<M){
    float acc=0.f;
    #pragma unroll 8
    for (int k=0;k<DIM;k++) acc += Xs2[rl*DIM+k]*Ws[k*OUTC+c];
    Y[(size_t)(row0+rl)*OUTC+c]=acc;
  }
}

// -------- SpMM gather (contiguous per-node edges, 4-deep unroll) + fused BN stats --------
__global__ __launch_bounds__(256) void k_spmm128(const unsigned short* __restrict__ sup,
    const unsigned int* __restrict__ sedge, const int* __restrict__ offs,
    unsigned short* __restrict__ h, int lbase, float* __restrict__ stL){
  int nl = threadIdx.x>>5;
  int node = blockIdx.x*8 + nl;
  int fq = threadIdx.x & 31;
  int p = offs[lbase+node], end = offs[lbase+node+1];
  float4 a0 = make_float4(0.f,0.f,0.f,0.f), a1 = a0, a2 = a0, a3 = a0;
  for (; p+3<end; p+=4){
    unsigned int e0 = __builtin_nontemporal_load(sedge+p);
    unsigned int e1 = __builtin_nontemporal_load(sedge+p+1);
    unsigned int e2 = __builtin_nontemporal_load(sedge+p+2);
    unsigned int e3 = __builtin_nontemporal_load(sedge+p+3);
    ushort4 s0 = *(const ushort4*)(sup + (size_t)(e0&0xFFFFu)*128 + fq*4);
    ushort4 s1 = *(const ushort4*)(sup + (size_t)(e1&0xFFFFu)*128 + fq*4);
    ushort4 s2 = *(const ushort4*)(sup + (size_t)(e2&0xFFFFu)*128 + fq*4);
    ushort4 s3 = *(const ushort4*)(sup + (size_t)(e3&0xFFFFu)*128 + fq*4);
    float w0 = __half2float(__ushort_as_half((unsigned short)(e0>>16)));
    float w1 = __half2float(__ushort_as_half((unsigned short)(e1>>16)));
    float w2 = __half2float(__ushort_as_half((unsigned short)(e2>>16)));
    float w3 = __half2float(__ushort_as_half((unsigned short)(e3>>16)));
    a0.x += w0*bf2f(s0.x); a0.y += w0*bf2f(s0.y); a0.z += w0*bf2f(s0.z); a0.w += w0*bf2f(s0.w);
    a1.x += w1*bf2f(s1.x); a1.y += w1*bf2f(s1.y); a1.z += w1*bf2f(s1.z); a1.w += w1*bf2f(s1.w);
    a2.x += w2*bf2f(s2.x); a2.y += w2*bf2f(s2.y); a2.z += w2*bf2f(s2.z); a2.w += w2*bf2f(s2.w);
    a3.x += w3*bf2f(s3.x); a3.y += w3*bf2f(s3.y); a3.z += w3*bf2f(s3.z); a3.w += w3*bf2f(s3.w);
  }
  for (; p<end; p++){
    unsigned int e0 = __builtin_nontemporal_load(sedge+p);
    float w0 = __half2float(__ushort_as_half((unsigned short)(e0>>16)));
    ushort4 s0 = *(const ushort4*)(sup + (size_t)(e0&0xFFFFu)*128 + fq*4);
    a0.x += w0*bf2f(s0.x); a0.y += w0*bf2f(s0.y); a0.z += w0*bf2f(s0.z); a0.w += w0*bf2f(s0.w);
  }
  a0.x+=a1.x+a2.x+a3.x; a0.y+=a1.y+a2.y+a3.y;
  a0.z+=a1.z+a2.z+a3.z; a0.w+=a1.w+a2.w+a3.w;
  ushort4 ov;
  ov.x=f2bf(a0.x); ov.y=f2bf(a0.y); ov.z=f2bf(a0.z); ov.w=f2bf(a0.w);
  *(ushort4*)(h + (size_t)node*128 + fq*4) = ov;
  // fused BN stats from fp32 registers
  __shared__ float sP[8][132], sQ[8][132];
  int f0 = fq*4;
  sP[nl][f0+0]=a0.x; sP[nl][f0+1]=a0.y; sP[nl][f0+2]=a0.z; sP[nl][f0+3]=a0.w;
  sQ[nl][f0+0]=a0.x*a0.x; sQ[nl][f0+1]=a0.y*a0.y; sQ[nl][f0+2]=a0.z*a0.z; sQ[nl][f0+3]=a0.w*a0.w;
  __syncthreads();
  if (threadIdx.x < 128){
    int f = threadIdx.x;
    float s=0.f, sq=0.f;
    #pragma unroll
    for (int n=0;n<8;n++){ s += sP[n][f]; sq += sQ[n][f]; }
    float* base = stL + (blockIdx.x & (NREP-1))*256;
    atomicAdd(&base[f], s); atomicAdd(&base[128+f], sq);
  }
}

__global__ __launch_bounds__(256) void k_spmm_out(const float* __restrict__ sup,
    const unsigned int* __restrict__ sedge, const int* __restrict__ offs,
    float* __restrict__ h, int lbase){
  int node = blockIdx.x*8 + (threadIdx.x>>5);
  int c = threadIdx.x & 31;
  int p = offs[lbase+node], end = offs[lbase+node+1];
  float acc=0.f;
  for (; p<end; p++){
    unsigned int e = __builtin_nontemporal_load(sedge+p);
    float w = __half2float(__ushort_as_half((unsigned short)(e>>16)));
    if (c<OUTC) acc += w*sup[(size_t)(e&0xFFFFu)*OUTC+c];
  }
  if (c<OUTC) h[(size_t)node*OUTC+c]=acc;
}

// ---------------- output-layer BN stats (8-way replicated) ----------------
__global__ __launch_bounds__(256) void k_bn_stats_out(const float* __restrict__ h,
    float* __restrict__ st8, int rpb){
  int f = threadIdx.x % 32;
  int g = threadIdx.x / 32;
  float s=0.f, ss=0.f;
  int r0 = blockIdx.x*rpb;
  int r1 = min(NN, r0+rpb);
  if (f < OUTC){
    for (int r=r0+g; r<r1; r+=8){ float v = h[(size_t)r*OUTC+f]; s+=v; ss+=v*v; }
  }
  __shared__ float sh[256], sh2[256];
  sh[threadIdx.x]=s; sh2[threadIdx.x]=ss; __syncthreads();
  if (threadIdx.x < 32){
    #pragma unroll
    for (int i=1;i<8;i++){ s+=sh[threadIdx.x+i*32]; ss+=sh2[threadIdx.x+i*32]; }
    if (f<OUTC){
      float* base = st8 + (blockIdx.x&7)*64;
      atomicAdd(&base[f], s); atomicAdd(&base[32+f], ss);
    }
  }
}

__global__ void k_bn_reduce8(const float* __restrict__ st8, float* __restrict__ st){
  int f = threadIdx.x;          // 64
  float s=0.f;
  #pragma unroll
  for (int g=0; g<8; g++) s += st8[g*64+f];
  st[f]=s;
}

__global__ void k_bn_out(float* __restrict__ h, const float* __restrict__ st,
    const float* __restrict__ gamma, const float* __restrict__ beta){
  int gid = blockIdx.x*256+threadIdx.x;
  if (gid>=NN*OUTC) return;
  int f = gid % OUTC;
  const float invN = 1.0f/NN;
  float m = st[f]*invN;
  float var = st[32+f]*invN - m*m;
  float sc = rsqrtf(var+BN_EPS)*gamma[f];
  h[gid] = fmaxf((h[gid]-m)*sc + beta[f], 0.f);
}

// ---------------- final masked reduce (8-way replicated) ----------------
__global__ __launch_bounds__(256) void k_reduce(const float* __restrict__ xf,
    const int* __restrict__ verts, const float* __restrict__ mw,
    float* __restrict__ acc8, int rpb){
  int c = threadIdx.x & 31, g = threadIdx.x >> 5;
  int r0 = blockIdx.x*rpb;
  int r1 = min(NN, r0+rpb);
  float s=0.f;
  for (int r=r0+g; r<r1; r+=8){
    float m = mw[verts[r]];
    if (c<OUTC) s += m * xf[(size_t)r*OUTC+c];
  }
  __shared__ float sh[256];
  sh[threadIdx.x]=s; __syncthreads();
  if (threadIdx.x<32){
    #pragma unroll
    for (int i=1;i<8;i++) s += sh[threadIdx.x + i*32];
    if (c<OUTC) atomicAdd(&acc8[(blockIdx.x&7)*32 + c], s);
  }
}

__global__ void k_final(const float* __restrict__ acc8, const float* __restrict__ mb,
                        float* __restrict__ out){
  int c=threadIdx.x;
  if (c<OUTC){
    float s=0.f;
    #pragma unroll
    for (int g=0; g<8; g++) s += acc8[g*32+c];
    out[c] = sigm(s+mb[c]);
  }
}

// ---------------- host ----------------
extern "C" void kernel_launch(void* const* d_in, const int* in_sizes, int n_in,
                              void* d_out, int out_size, void* d_ws, size_t ws_size,
                              hipStream_t stream){
  const int*   verts = (const int*)d_in[0];
  const int*   ei    = (const int*)d_in[1];
  const float* ew    = (const float*)d_in[2];
  const float* emb   = (const float*)d_in[3];
  const float* wh    = (const float*)d_in[4];
  const float* w_out = (const float*)d_in[6];
  const float* bng_h = (const float*)d_in[8];
  const float* bnb_h = (const float*)d_in[9];
  const float* bng_o = (const float*)d_in[10];
  const float* bnb_o = (const float*)d_in[11];
  const float* tewl  = (const float*)d_in[12];
  const float* tewc  = (const float*)d_in[13];
  const float* teb   = (const float*)d_in[14];
  const float* maskw = (const float*)d_in[15];
  const float* maskb = (const float*)d_in[16];
  float* out = (float*)d_out;

  char* ws = (char*)d_ws;
  size_t off=0;
  auto alloc=[&](size_t bytes)->char*{ char* p = ws+off; off += (bytes+255)&~(size_t)255; return p; };
  unsigned int* sedge = (unsigned int*)alloc(sizeof(int)*LE);   // 22.4 MB
  int*   offs   = (int*)  alloc(sizeof(int)*(LN+1));            // 1.4 MB
  int*   Gm     = (int*)  alloc(sizeof(int)*LL*NBLK*GMS);       // 0.7 MB
  int*   S      = (int*)  alloc(sizeof(int)*(SCN+1));           // 0.7 MB
  int*   bsums  = (int*)  alloc(sizeof(int)*1024);
  unsigned short* xbf   = (unsigned short*)alloc(sizeof(short)*NN*DIM); // 12.8 MB
  unsigned short* supbf = (unsigned short*)alloc(sizeof(short)*NN*DIM); // 12.8 MB
  unsigned short* hbf   = (unsigned short*)alloc(sizeof(short)*NN*DIM); // 12.8 MB
  float* buf20  = (float*)alloc(sizeof(float)*NN*OUTC);         // 4 MB
  unsigned short* Wt = (unsigned short*)alloc(sizeof(short)*18*DIM*DIM);
  const int STATSZ = 6*NREP*256 + 8*64 + 64 + 8*32;
  float* stats  = (float*)alloc(sizeof(float)*STATSZ);
  float* ostat8 = stats + 6*NREP*256;  // [8][64]
  float* ostat  = ostat8 + 8*64;       // [64]
  float* racc8  = ostat + 64;          // [8][32]
  // btmpP (22.4 MB) aliases xbf+supbf (25.6 MB contiguous); btmpD (5.6 MB) aliases hbf
  unsigned int*  btmpP = (unsigned int*)xbf;
  unsigned char* btmpD = (unsigned char*)hbf;

  // --- preprocessing: 4-pass LDS-atomic counting sort ---
  hipMemsetAsync(stats, 0, sizeof(float)*STATSZ, stream);
  k_prep_w<<<1152,256,0,stream>>>(wh, tewl, tewc, Wt);
  k_bh<<<LL*NBLK,256,0,stream>>>(ei, Gm);
  int nsb = (SCN+4095)/4096;  // 43
  k_scan1p<<<nsb,256,0,stream>>>(Gm, S, bsums);
  k_scan2<<<1,1024,0,stream>>>(bsums, nsb);
  k_scan3<<<(SCN+255)/256,256,0,stream>>>(S, bsums);
  k_bscatter<<<LL*NBLK,256,0,stream>>>(ei, ew, S, btmpP, btmpD);
  k_fsort<<<LL*NBUK,256,0,stream>>>(btmpP, btmpD, S, sedge, offs);
  k_gather_emb<<<NN*16/256,256,0,stream>>>(verts, emb, xbf);

  // --- 6 hidden layers; sup for layer i+1 computed inside gate2 of layer i ---
  k_gemm_sup<<<(NN+63)/64,256,0,stream>>>(xbf, Wt, supbf, NN);
  for (int i=0;i<6;i++){
    int j = (i==0)?5:(i-1);
    float* stL = stats + i*NREP*256;
    k_spmm128<<<NN/8,256,0,stream>>>(supbf, sedge, offs, hbf, i*NN, stL);
    if (i<5)
      k_gemm_gate2<1><<<(NN+63)/64,256,0,stream>>>(hbf, stL,
          bng_h+(size_t)i*DIM, bnb_h+(size_t)i*DIM,
          Wt + (size_t)(6+j)*DIM*DIM, Wt + (size_t)(12+j)*DIM*DIM,
          Wt + (size_t)(i+1)*DIM*DIM, teb + (size_t)j*DIM, xbf, supbf, NN);
    else
      k_gemm_gate2<0><<<(NN+63)/64,256,0,stream>>>(hbf, stL,
          bng_h+(size_t)i*DIM, bnb_h+(size_t)i*DIM,
          Wt + (size_t)(6+j)*DIM*DIM, Wt + (size_t)(12+j)*DIM*DIM,
          Wt, teb + (size_t)j*DIM, xbf, supbf, NN);
  }

  // --- output layer (fp32 accumulate) ---
  k_gemm_out<<<(NN+7)/8,256,0,stream>>>(xbf, w_out, buf20, NN);
  k_spmm_out<<<NN/8,256,0,stream>>>(buf20, sedge, offs, (float*)hbf, 6*NN);
  float* bufO = (float*)hbf;   // NN*OUTC fp32 = 4 MB <= 12.8 MB
  k_bn_stats_out<<<512,256,0,stream>>>(bufO, ostat8, 98);
  k_bn_reduce8<<<1,64,0,stream>>>(ostat8, ostat);
  k_bn_out<<<(NN*OUTC+255)/256,256,0,stream>>>(bufO, ostat, bng_o, bnb_o);
  k_reduce<<<512,256,0,stream>>>(bufO, verts, maskw, racc8, 98);
  k_final<<<1,64,0,stream>>>(racc8, maskb, out);
}

// Round 13
// 991.633 us; speedup vs baseline: 1.0305x; 1.0305x over previous
//
#include <hip/hip_runtime.h>
#include <hip/hip_fp16.h>

#define NN 50000
#define EE 800000
#define DIM 128
#define OUTC 20
#define LL 7
#define LE (LL*EE)
#define LN (LL*NN)
#define BN_EPS 1e-5f
#define LSTRIDE 136     // bf16 elems per LDS row
#define NREP 64         // BN stat replicas
#define NBUK 196        // coarse buckets of 256 dsts per layer
#define GMS  200        // padded Gm stride
#define NBLK 200        // edge-blocks per layer (EE/NBLK = 4000)
#define CH   4000
#define SCN  (LL*NBUK*NBLK)   // 274400 scan entries

typedef __attribute__((ext_vector_type(8))) short short8;
typedef __attribute__((ext_vector_type(4))) float f32x4;

static __device__ __forceinline__ float sigm(float z){ return 1.0f/(1.0f+expf(-z)); }
static __device__ __forceinline__ unsigned short f2bf(float f){
  unsigned int u = __float_as_uint(f);
  u += 0x7FFF + ((u>>16)&1);            // RNE
  return (unsigned short)(u>>16);
}
static __device__ __forceinline__ float bf2f(unsigned short s){
  return __uint_as_float(((unsigned int)s)<<16);
}

// ======== preprocessing: counting sort, all atomics in LDS, pure streaming ========

// P1: per-(layer,block) LDS histogram over 196 coarse buckets
__global__ __launch_bounds__(256) void k_bh(const int* __restrict__ ei,
    int* __restrict__ Gm){
  int l = blockIdx.x / NBLK, b = blockIdx.x - l*NBLK;
  int t = threadIdx.x;
  __shared__ int h[NBUK];
  if (t<NBUK) h[t]=0;
  __syncthreads();
  const int* dsts = ei + (size_t)(2*l+1)*EE + b*CH;
  for (int k=t; k<CH; k+=256) atomicAdd(&h[__builtin_nontemporal_load(dsts+k)>>8], 1);
  __syncthreads();
  int* g = Gm + (size_t)(l*NBLK+b)*GMS;
  if (t<NBUK) g[t]=h[t];
}

// P2: exclusive scan over (l,buk,b) enumeration of Gm[(l,b),buk]
__global__ __launch_bounds__(256) void k_scan1p(const int* __restrict__ Gm,
    int* __restrict__ part, int* __restrict__ bsums){
  __shared__ int s[256];
  int t = threadIdx.x;
  int base = blockIdx.x*4096 + t*16;
  int v[16]; int sum = 0;
  #pragma unroll
  for (int i=0;i<16;i++){
    int idx = base+i; int val = 0;
    if (idx < SCN){
      int l = idx/(NBUK*NBLK);
      int r = idx - l*(NBUK*NBLK);
      int buk = r/NBLK, b = r - buk*NBLK;
      val = Gm[(size_t)(l*NBLK+b)*GMS + buk];
    }
    v[i]=val; sum+=val;
  }
  s[t]=sum; __syncthreads();
  for (int off=1; off<256; off<<=1){
    int x = (t>=off)? s[t-off] : 0;
    __syncthreads(); s[t]+=x; __syncthreads();
  }
  if (t==255) bsums[blockIdx.x] = s[255];
  int run = s[t]-sum;
  #pragma unroll
  for (int i=0;i<16;i++){ if (base+i<SCN) part[base+i]=run; run += v[i]; }
}

__global__ __launch_bounds__(1024) void k_scan2(int* bsums, int nb){
  __shared__ int s[1024];
  int t=threadIdx.x;
  int v = (t<nb)? bsums[t]:0;
  s[t]=v; __syncthreads();
  for (int off=1; off<1024; off<<=1){
    int x=(t>=off)? s[t-off]:0; __syncthreads(); s[t]+=x; __syncthreads();
  }
  if (t<nb) bsums[t] = s[t]-v;
}

__global__ void k_scan3(int* __restrict__ S, const int* __restrict__ bsums){
  int gid = blockIdx.x*256+threadIdx.x;
  if (gid < SCN) S[gid] += bsums[gid>>12];
  if (gid==0) S[SCN]=LE;
}

// P3: LDS counting-sort by bucket with FINAL payload stored at placement
// (no random re-reads); write pass is pure LDS-seq -> global-stream.
__global__ __launch_bounds__(256) void k_bscatter(const int* __restrict__ ei,
    const float* __restrict__ ew, const int* __restrict__ S,
    unsigned int* __restrict__ btmpP, unsigned char* __restrict__ btmpD){
  int l = blockIdx.x / NBLK, b = blockIdx.x - l*NBLK;
  int t = threadIdx.x;
  __shared__ int cnt[NBUK], bstart[NBUK], cur[NBUK], runb[NBUK];
  __shared__ int ps[256];
  __shared__ unsigned int  ebP[CH];     // 16 KB: src16|halfw16
  __shared__ unsigned short ebM[CH];    // 8 KB:  dlow8|buk8
  if (t<NBUK) cnt[t]=0;
  __syncthreads();
  const int* srcs = ei + (size_t)(2*l)*EE + b*CH;
  const int* dsts = ei + (size_t)(2*l+1)*EE + b*CH;
  const float* wsrc = ew + (size_t)l*EE + b*CH;
  for (int k=t;k<CH;k+=256) atomicAdd(&cnt[dsts[k]>>8],1);
  __syncthreads();
  // exclusive scan over 196 counts (1 per thread)
  int v = (t<NBUK)? cnt[t]:0;
  ps[t]=v; __syncthreads();
  for (int o=1;o<256;o<<=1){ int x=(t>=o)?ps[t-o]:0; __syncthreads(); ps[t]+=x; __syncthreads(); }
  if (t<NBUK){ bstart[t]=ps[t]-v; cur[t]=ps[t]-v; runb[t] = S[(size_t)(l*NBUK+t)*NBLK + b]; }
  __syncthreads();
  // place final records into LDS in bucket order (all inputs read sequentially)
  for (int k=t;k<CH;k+=256){
    int dst = dsts[k];
    int src = srcs[k];
    float w = wsrc[k];
    int buk = dst>>8;
    int pos = atomicAdd(&cur[buk],1);
    unsigned short hw = __half_as_ushort(__float2half(w));
    ebP[pos] = (unsigned)src | ((unsigned)hw<<16);
    ebM[pos] = (unsigned short)((dst&255) | (buk<<8));
  }
  __syncthreads();
  // streaming write: each bucket run contiguous in LDS and global
  for (int k=t;k<CH;k+=256){
    unsigned short m = ebM[k];
    int buk = m>>8;
    int gp = runb[buk] + (k - bstart[buk]);
    btmpP[gp] = ebP[k];
    btmpD[gp] = (unsigned char)(m&255);
  }
}

// P4: per-bucket (256 dsts) count+scan from 1B dst array, direct scatter of packed edges
__global__ __launch_bounds__(256) void k_fsort(const unsigned int* __restrict__ btmpP,
    const unsigned char* __restrict__ btmpD, const int* __restrict__ S,
    unsigned int* __restrict__ sedge, int* __restrict__ offs){
  int lbuk = blockIdx.x;                 // 0..1371
  int l = lbuk/NBUK, bl = lbuk - l*NBUK;
  int t = threadIdx.x;
  int base = S[(size_t)lbuk*NBLK];
  int end  = S[(size_t)(lbuk+1)*NBLK];
  int nE = end - base;
  __shared__ int cnt[256], sc[256];
  cnt[t]=0;
  __syncthreads();
  for (int k=t; k<nE; k+=256) atomicAdd(&cnt[btmpD[base+k]], 1);
  __syncthreads();
  int c = cnt[t];
  sc[t]=c;
  __syncthreads();
  for (int o=1;o<256;o<<=1){
    int v = (t>=o)? sc[t-o]:0;
    __syncthreads();
    sc[t]+=v;
    __syncthreads();
  }
  {
    int excl = sc[t]-c;
    int node = bl*256+t;
    if (node<NN) offs[(size_t)l*NN+node] = base + excl;
    cnt[t] = base + excl;                // becomes cursor
  }
  if (lbuk==0 && t==255) offs[LN]=LE;
  __syncthreads();
  for (int k=t; k<nE; k+=256){
    int d = btmpD[base+k];
    int r = atomicAdd(&cnt[d],1);
    sedge[r] = btmpP[base+k];
  }
}

// ---- transpose + bf16-convert all 18 hidden weight matrices: Wt[m][n][k] ----
__global__ __launch_bounds__(256) void k_prep_w(const float* __restrict__ wh,
    const float* __restrict__ tewl, const float* __restrict__ tewc,
    unsigned short* __restrict__ Wt){
  int gid = blockIdx.x*256+threadIdx.x;          // 18*16384
  int m = gid>>14; int idx = gid&16383;
  int n = idx>>7, k = idx&127;
  const float* src = (m<6)? wh + (size_t)m*16384
                   : (m<12)? tewl + (size_t)(m-6)*16384
                   : tewc + (size_t)(m-12)*16384;
  Wt[gid] = f2bf(src[k*128+n]);
}

// stage 64 bf16 rows -> LDS tile [64][LSTRIDE]
static __device__ __forceinline__ void stage64bf(const unsigned short* __restrict__ src,
    int row0, int M, unsigned short* Xs, int tid){
  #pragma unroll
  for (int it=0; it<4; it++){
    int idx = tid + it*256;
    int r = idx>>4, k8 = idx&15;
    short8 v = short8(0);
    if (row0+r < M) v = *(const short8*)(src + (size_t)(row0+r)*128 + k8*8);
    *(short8*)&Xs[r*LSTRIDE + k8*8] = v;
  }
}

// -------- MFMA GEMM layer 0: gather emb rows, convert, write xbf, compute sup --------
__global__ __launch_bounds__(256) void k_gemm_sup_emb(const int* __restrict__ verts,
    const float* __restrict__ emb, const unsigned short* __restrict__ Wt,
    unsigned short* __restrict__ Y, unsigned short* __restrict__ xout, int M){
  __shared__ unsigned short Xs[64*LSTRIDE];
  int tid = threadIdx.x;
  int row0 = blockIdx.x*64;
  #pragma unroll
  for (int it=0; it<4; it++){
    int idx = tid + it*256;
    int r = idx>>4, k8 = idx&15;
    short8 w = short8(0);
    if (row0+r < M){
      int v = verts[row0+r];
      const float4* p = (const float4*)emb + (size_t)v*32 + k8*2;
      float4 v0 = p[0], v1 = p[1];
      w[0]=(short)f2bf(v0.x); w[1]=(short)f2bf(v0.y); w[2]=(short)f2bf(v0.z); w[3]=(short)f2bf(v0.w);
      w[4]=(short)f2bf(v1.x); w[5]=(short)f2bf(v1.y); w[6]=(short)f2bf(v1.z); w[7]=(short)f2bf(v1.w);
      *(short8*)(xout + (size_t)(row0+r)*128 + k8*8) = w;
    }
    *(short8*)&Xs[r*LSTRIDE + k8*8] = w;
  }
  __syncthreads();
  int w = tid>>6, lane = tid&63, m = lane&15, q = lane>>4;
  f32x4 acc[8];
  #pragma unroll
  for (int nt=0;nt<8;nt++){ acc[nt][0]=0.f; acc[nt][1]=0.f; acc[nt][2]=0.f; acc[nt][3]=0.f; }
  #pragma unroll
  for (int kc=0; kc<4; kc++){
    short8 a = *(const short8*)&Xs[(16*w+m)*LSTRIDE + kc*32 + 8*q];
    #pragma unroll
    for (int nt=0; nt<8; nt++){
      short8 b = *(const short8*)&Wt[(size_t)(nt*16+m)*128 + kc*32 + 8*q];
      acc[nt] = __builtin_amdgcn_mfma_f32_16x16x32_bf16(a, b, acc[nt], 0,0,0);
    }
  }
  #pragma unroll
  for (int nt=0; nt<8; nt++){
    #pragma unroll
    for (int i=0;i<4;i++){
      int rr = row0 + 16*w + 4*q + i;
      if (rr<M) Y[(size_t)rr*128 + nt*16 + m] = f2bf(acc[nt][i]);
    }
  }
}

// ------- fused: BN(bf16 h)+ReLU -> LDS; dual MFMA; gate; short8 writeback; [+ next sup] -------
template<int FUSE>
__global__ __launch_bounds__(256) void k_gemm_gate2(const unsigned short* __restrict__ H,
    const float* __restrict__ stL,            // NREP replicas [rep][sum128|sq128]
    const float* __restrict__ gamma, const float* __restrict__ beta,
    const unsigned short* __restrict__ Wl, const unsigned short* __restrict__ Wc,
    const unsigned short* __restrict__ Wn, const float* __restrict__ teb,
    unsigned short* __restrict__ x, unsigned short* __restrict__ supY, int M){
  __shared__ unsigned short XsX[64*LSTRIDE];
  __shared__ unsigned short XsH[64*LSTRIDE];
  __shared__ float sSc[128], sOff[128];
  int tid = threadIdx.x;
  int row0 = blockIdx.x*64;
  if (tid<128){
    float s=0.f, sq=0.f;
    #pragma unroll 8
    for (int g=0; g<NREP; g++){ s += stL[g*256+tid]; sq += stL[g*256+128+tid]; }
    float mean = s*(1.0f/NN);
    float var = sq*(1.0f/NN) - mean*mean;
    float sc = rsqrtf(var+BN_EPS)*gamma[tid];
    sSc[tid]=sc; sOff[tid]=beta[tid]-mean*sc;
  }
  stage64bf(x, row0, M, XsX, tid);
  __syncthreads();
  #pragma unroll
  for (int it=0; it<4; it++){
    int idx = tid + it*256;
    int r = idx>>4, k8 = idx&15;
    short8 hv8 = short8(0);
    if (row0+r < M) hv8 = *(const short8*)(H + (size_t)(row0+r)*128 + k8*8);
    int k = k8*8;
    short8 w;
    #pragma unroll
    for (int j=0;j<8;j++){
      float o = bf2f((unsigned short)hv8[j]);
      float hn = fmaxf(fmaf(o, sSc[k+j], sOff[k+j]), 0.f);
      w[j] = (short)f2bf(hn);
    }
    *(short8*)&XsH[r*LSTRIDE + k8*8] = w;
  }
  __syncthreads();
  int w = tid>>6, lane = tid&63, m = lane&15, q = lane>>4;
  f32x4 acc[8];
  #pragma unroll
  for (int nt=0;nt<8;nt++){ acc[nt][0]=0.f; acc[nt][1]=0.f; acc[nt][2]=0.f; acc[nt][3]=0.f; }
  #pragma unroll
  for (int kc=0; kc<4; kc++){
    short8 a = *(const short8*)&XsX[(16*w+m)*LSTRIDE + kc*32 + 8*q];
    #pragma unroll
    for (int nt=0; nt<8; nt++){
      short8 b = *(const short8*)&Wl[(size_t)(nt*16+m)*128 + kc*32 + 8*q];
      acc[nt] = __builtin_amdgcn_mfma_f32_16x16x32_bf16(a, b, acc[nt], 0,0,0);
    }
  }
  #pragma unroll
  for (int kc=0; kc<4; kc++){
    short8 a = *(const short8*)&XsH[(16*w+m)*LSTRIDE + kc*32 + 8*q];
    #pragma unroll
    for (int nt=0; nt<8; nt++){
      short8 b = *(const short8*)&Wc[(size_t)(nt*16+m)*128 + kc*32 + 8*q];
      acc[nt] = __builtin_amdgcn_mfma_f32_16x16x32_bf16(a, b, acc[nt], 0,0,0);
    }
  }
  // gate epilogue: write xn into XsH (each cell owned by one thread), XsX too if FUSE
  #pragma unroll
  for (int nt=0; nt<8; nt++){
    int col = nt*16 + m;
    float bias = teb[col];
    #pragma unroll
    for (int i=0;i<4;i++){
      int lr = 16*w + 4*q + i;
      float hv = bf2f(XsH[lr*LSTRIDE + col]);
      float xo = bf2f(XsX[lr*LSTRIDE + col]);
      float g = sigm(acc[nt][i] + bias);
      unsigned short xnb = f2bf(g*hv + (1.f-g)*xo);
      XsH[lr*LSTRIDE + col] = xnb;
      if (FUSE) XsX[lr*LSTRIDE + col] = xnb;
    }
  }
  __syncthreads();
  // coalesced short8 writeback of x_new
  #pragma unroll
  for (int it=0; it<4; it++){
    int idx = tid + it*256;
    int r = idx>>4, k8 = idx&15;
    if (row0+r < M)
      *(short8*)(x + (size_t)(row0+r)*128 + k8*8) = *(short8*)&XsH[r*LSTRIDE + k8*8];
  }
  if (FUSE){
    #pragma unroll
    for (int nt=0;nt<8;nt++){ acc[nt][0]=0.f; acc[nt][1]=0.f; acc[nt][2]=0.f; acc[nt][3]=0.f; }
    #pragma unroll
    for (int kc=0; kc<4; kc++){
      short8 a = *(const short8*)&XsX[(16*w+m)*LSTRIDE + kc*32 + 8*q];
      #pragma unroll
      for (int nt=0; nt<8; nt++){
        short8 b = *(const short8*)&Wn[(size_t)(nt*16+m)*128 + kc*32 + 8*q];
        acc[nt] = __builtin_amdgcn_mfma_f32_16x16x32_bf16(a, b, acc[nt], 0,0,0);
      }
    }
    #pragma unroll
    for (int nt=0; nt<8; nt++){
      #pragma unroll
      for (int i=0;i<4;i++){
        int rr = row0 + 16*w + 4*q + i;
        if (rr<M) supY[(size_t)rr*128 + nt*16 + m] = f2bf(acc[nt][i]);
      }
    }
  }
}

// ---------------- Y[M,20] = bf16 X[M,128] @ W[128,20] (fp32 acc) ----------------
__global__ __launch_bounds__(256) void k_gemm_out(const unsigned short* __restrict__ X,
    const float* __restrict__ W, float* __restrict__ Y, int M){
  __shared__ float Ws[DIM*OUTC];
  __shared__ float Xs2[8*DIM];
  int tid=threadIdx.x;
  for (int i=tid;i<DIM*OUTC;i+=256) Ws[i]=W[i];
  int row0=blockIdx.x*8;
  if (tid<128){
    int r = tid>>4, k8 = tid&15;
    short8 v = short8(0);
    if (row0+r<M) v = *(const short8*)(X + (size_t)(row0+r)*128 + k8*8);
    #pragma unroll
    for (int j=0;j<8;j++) Xs2[r*DIM+k8*8+j] = bf2f((unsigned short)v[j]);
  }
  __syncthreads();
  int c = tid&31, rl=tid>>5;
  if (c<OUTC && row0+rl<M){
    float acc=0.f;
    #pragma unroll 8
    for (int k=0;k<DIM;k++) acc += Xs2[rl*DIM+k]*Ws[k*OUTC+c];
    Y[(size_t)(row0+rl)*OUTC+c]=acc;
  }
}

// -------- SpMM gather (contiguous per-node edges, 4-deep unroll) + fused BN stats --------
__global__ __launch_bounds__(256) void k_spmm128(const unsigned short* __restrict__ sup,
    const unsigned int* __restrict__ sedge, const int* __restrict__ offs,
    unsigned short* __restrict__ h, int lbase, float* __restrict__ stL){
  int nl = threadIdx.x>>5;
  int node = blockIdx.x*8 + nl;
  int fq = threadIdx.x & 31;
  int p = offs[lbase+node], end = offs[lbase+node+1];
  float4 a0 = make_float4(0.f,0.f,0.f,0.f), a1 = a0, a2 = a0, a3 = a0;
  for (; p+3<end; p+=4){
    unsigned int e0 = __builtin_nontemporal_load(sedge+p);
    unsigned int e1 = __builtin_nontemporal_load(sedge+p+1);
    unsigned int e2 = __builtin_nontemporal_load(sedge+p+2);
    unsigned int e3 = __builtin_nontemporal_load(sedge+p+3);
    ushort4 s0 = *(const ushort4*)(sup + (size_t)(e0&0xFFFFu)*128 + fq*4);
    ushort4 s1 = *(const ushort4*)(sup + (size_t)(e1&0xFFFFu)*128 + fq*4);
    ushort4 s2 = *(const ushort4*)(sup + (size_t)(e2&0xFFFFu)*128 + fq*4);
    ushort4 s3 = *(const ushort4*)(sup + (size_t)(e3&0xFFFFu)*128 + fq*4);
    float w0 = __half2float(__ushort_as_half((unsigned short)(e0>>16)));
    float w1 = __half2float(__ushort_as_half((unsigned short)(e1>>16)));
    float w2 = __half2float(__ushort_as_half((unsigned short)(e2>>16)));
    float w3 = __half2float(__ushort_as_half((unsigned short)(e3>>16)));
    a0.x += w0*bf2f(s0.x); a0.y += w0*bf2f(s0.y); a0.z += w0*bf2f(s0.z); a0.w += w0*bf2f(s0.w);
    a1.x += w1*bf2f(s1.x); a1.y += w1*bf2f(s1.y); a1.z += w1*bf2f(s1.z); a1.w += w1*bf2f(s1.w);
    a2.x += w2*bf2f(s2.x); a2.y += w2*bf2f(s2.y); a2.z += w2*bf2f(s2.z); a2.w += w2*bf2f(s2.w);
    a3.x += w3*bf2f(s3.x); a3.y += w3*bf2f(s3.y); a3.z += w3*bf2f(s3.z); a3.w += w3*bf2f(s3.w);
  }
  for (; p<end; p++){
    unsigned int e0 = __builtin_nontemporal_load(sedge+p);
    float w0 = __half2float(__ushort_as_half((unsigned short)(e0>>16)));
    ushort4 s0 = *(const ushort4*)(sup + (size_t)(e0&0xFFFFu)*128 + fq*4);
    a0.x += w0*bf2f(s0.x); a0.y += w0*bf2f(s0.y); a0.z += w0*bf2f(s0.z); a0.w += w0*bf2f(s0.w);
  }
  a0.x+=a1.x+a2.x+a3.x; a0.y+=a1.y+a2.y+a3.y;
  a0.z+=a1.z+a2.z+a3.z; a0.w+=a1.w+a2.w+a3.w;
  ushort4 ov;
  ov.x=f2bf(a0.x); ov.y=f2bf(a0.y); ov.z=f2bf(a0.z); ov.w=f2bf(a0.w);
  *(ushort4*)(h + (size_t)node*128 + fq*4) = ov;
  // fused BN stats from fp32 registers
  __shared__ float sP[8][132], sQ[8][132];
  int f0 = fq*4;
  sP[nl][f0+0]=a0.x; sP[nl][f0+1]=a0.y; sP[nl][f0+2]=a0.z; sP[nl][f0+3]=a0.w;
  sQ[nl][f0+0]=a0.x*a0.x; sQ[nl][f0+1]=a0.y*a0.y; sQ[nl][f0+2]=a0.z*a0.z; sQ[nl][f0+3]=a0.w*a0.w;
  __syncthreads();
  if (threadIdx.x < 128){
    int f = threadIdx.x;
    float s=0.f, sq=0.f;
    #pragma unroll
    for (int n=0;n<8;n++){ s += sP[n][f]; sq += sQ[n][f]; }
    float* base = stL + (blockIdx.x & (NREP-1))*256;
    atomicAdd(&base[f], s); atomicAdd(&base[128+f], sq);
  }
}

__global__ __launch_bounds__(256) void k_spmm_out(const float* __restrict__ sup,
    const unsigned int* __restrict__ sedge, const int* __restrict__ offs,
    float* __restrict__ h, int lbase){
  int node = blockIdx.x*8 + (threadIdx.x>>5);
  int c = threadIdx.x & 31;
  int p = offs[lbase+node], end = offs[lbase+node+1];
  float acc=0.f;
  for (; p<end; p++){
    unsigned int e = __builtin_nontemporal_load(sedge+p);
    float w = __half2float(__ushort_as_half((unsigned short)(e>>16)));
    if (c<OUTC) acc += w*sup[(size_t)(e&0xFFFFu)*OUTC+c];
  }
  if (c<OUTC) h[(size_t)node*OUTC+c]=acc;
}

// ---------------- output-layer BN stats (8-way replicated) ----------------
__global__ __launch_bounds__(256) void k_bn_stats_out(const float* __restrict__ h,
    float* __restrict__ st8, int rpb){
  int f = threadIdx.x % 32;
  int g = threadIdx.x / 32;
  float s=0.f, ss=0.f;
  int r0 = blockIdx.x*rpb;
  int r1 = min(NN, r0+rpb);
  if (f < OUTC){
    for (int r=r0+g; r<r1; r+=8){ float v = h[(size_t)r*OUTC+f]; s+=v; ss+=v*v; }
  }
  __shared__ float sh[256], sh2[256];
  sh[threadIdx.x]=s; sh2[threadIdx.x]=ss; __syncthreads();
  if (threadIdx.x < 32){
    #pragma unroll
    for (int i=1;i<8;i++){ s+=sh[threadIdx.x+i*32]; ss+=sh2[threadIdx.x+i*32]; }
    if (f<OUTC){
      float* base = st8 + (blockIdx.x&7)*64;
      atomicAdd(&base[f], s); atomicAdd(&base[32+f], ss);
    }
  }
}

// ---------- fused: BN-normalize+ReLU inline + masked reduce (8-way replicated) ----------
__global__ __launch_bounds__(256) void k_reduce(const float* __restrict__ xf,
    const float* __restrict__ st8, const float* __restrict__ gamma,
    const float* __restrict__ beta, const int* __restrict__ verts,
    const float* __restrict__ mw, float* __restrict__ acc8, int rpb){
  int c = threadIdx.x & 31, g = threadIdx.x >> 5;
  float scn=0.f, offc=0.f;
  if (c<OUTC){
    float s=0.f, sq=0.f;
    #pragma unroll
    for (int i=0;i<8;i++){ s += st8[i*64+c]; sq += st8[i*64+32+c]; }
    const float invN = 1.0f/NN;
    float m = s*invN;
    float var = sq*invN - m*m;
    scn = rsqrtf(var+BN_EPS)*gamma[c];
    offc = beta[c] - m*scn;
  }
  int r0 = blockIdx.x*rpb;
  int r1 = min(NN, r0+rpb);
  float s=0.f;
  for (int r=r0+g; r<r1; r+=8){
    float m = mw[verts[r]];
    if (c<OUTC){
      float v = fmaxf(fmaf(xf[(size_t)r*OUTC+c], scn, offc), 0.f);
      s += m * v;
    }
  }
  __shared__ float sh[256];
  sh[threadIdx.x]=s; __syncthreads();
  if (threadIdx.x<32){
    #pragma unroll
    for (int i=1;i<8;i++) s += sh[threadIdx.x + i*32];
    if (c<OUTC) atomicAdd(&acc8[(blockIdx.x&7)*32 + c], s);
  }
}

__global__ void k_final(const float* __restrict__ acc8, const float* __restrict__ mb,
                        float* __restrict__ out){
  int c=threadIdx.x;
  if (c<OUTC){
    float s=0.f;
    #pragma unroll
    for (int g=0; g<8; g++) s += acc8[g*32+c];
    out[c] = sigm(s+mb[c]);
  }
}

// ---------------- host ----------------
extern "C" void kernel_launch(void* const* d_in, const int* in_sizes, int n_in,
                              void* d_out, int out_size, void* d_ws, size_t ws_size,
                              hipStream_t stream){
  const int*   verts = (const int*)d_in[0];
  const int*   ei    = (const int*)d_in[1];
  const float* ew    = (const float*)d_in[2];
  const float* emb   = (const float*)d_in[3];
  const float* wh    = (const float*)d_in[4];
  const float* w_out = (const float*)d_in[6];
  const float* bng_h = (const float*)d_in[8];
  const float* bnb_h = (const float*)d_in[9];
  const float* bng_o = (const float*)d_in[10];
  const float* bnb_o = (const float*)d_in[11];
  const float* tewl  = (const float*)d_in[12];
  const float* tewc  = (const float*)d_in[13];
  const float* teb   = (const float*)d_in[14];
  const float* maskw = (const float*)d_in[15];
  const float* maskb = (const float*)d_in[16];
  float* out = (float*)d_out;

  char* ws = (char*)d_ws;
  size_t off=0;
  auto alloc=[&](size_t bytes)->char*{ char* p = ws+off; off += (bytes+255)&~(size_t)255; return p; };
  unsigned int* sedge = (unsigned int*)alloc(sizeof(int)*LE);   // 22.4 MB
  int*   offs   = (int*)  alloc(sizeof(int)*(LN+1));            // 1.4 MB
  int*   Gm     = (int*)  alloc(sizeof(int)*LL*NBLK*GMS);       // 1.1 MB
  int*   S      = (int*)  alloc(sizeof(int)*(SCN+1));           // 1.1 MB
  int*   bsums  = (int*)  alloc(sizeof(int)*1024);
  unsigned short* xbf   = (unsigned short*)alloc(sizeof(short)*NN*DIM); // 12.8 MB
  unsigned short* supbf = (unsigned short*)alloc(sizeof(short)*NN*DIM); // 12.8 MB
  unsigned short* hbf   = (unsigned short*)alloc(sizeof(short)*NN*DIM); // 12.8 MB
  float* buf20  = (float*)alloc(sizeof(float)*NN*OUTC);         // 4 MB
  unsigned short* Wt = (unsigned short*)alloc(sizeof(short)*18*DIM*DIM);
  const int STATSZ = 6*NREP*256 + 8*64 + 8*32;
  float* stats  = (float*)alloc(sizeof(float)*STATSZ);
  float* ostat8 = stats + 6*NREP*256;  // [8][64]
  float* racc8  = ostat8 + 8*64;       // [8][32]
  // btmpP (22.4 MB) aliases xbf+supbf (25.6 MB contiguous); btmpD (5.6 MB) aliases hbf
  unsigned int*  btmpP = (unsigned int*)xbf;
  unsigned char* btmpD = (unsigned char*)hbf;

  // --- preprocessing: 4-pass LDS-atomic counting sort ---
  hipMemsetAsync(stats, 0, sizeof(float)*STATSZ, stream);
  k_prep_w<<<1152,256,0,stream>>>(wh, tewl, tewc, Wt);
  k_bh<<<LL*NBLK,256,0,stream>>>(ei, Gm);
  int nsb = (SCN+4095)/4096;  // 68
  k_scan1p<<<nsb,256,0,stream>>>(Gm, S, bsums);
  k_scan2<<<1,1024,0,stream>>>(bsums, nsb);
  k_scan3<<<(SCN+255)/256,256,0,stream>>>(S, bsums);
  k_bscatter<<<LL*NBLK,256,0,stream>>>(ei, ew, S, btmpP, btmpD);
  k_fsort<<<LL*NBUK,256,0,stream>>>(btmpP, btmpD, S, sedge, offs);

  // --- 6 hidden layers; sup for layer i+1 computed inside gate2 of layer i ---
  k_gemm_sup_emb<<<(NN+63)/64,256,0,stream>>>(verts, emb, Wt, supbf, xbf, NN);
  for (int i=0;i<6;i++){
    int j = (i==0)?5:(i-1);
    float* stL = stats + i*NREP*256;
    k_spmm128<<<NN/8,256,0,stream>>>(supbf, sedge, offs, hbf, i*NN, stL);
    if (i<5)
      k_gemm_gate2<1><<<(NN+63)/64,256,0,stream>>>(hbf, stL,
          bng_h+(size_t)i*DIM, bnb_h+(size_t)i*DIM,
          Wt + (size_t)(6+j)*DIM*DIM, Wt + (size_t)(12+j)*DIM*DIM,
          Wt + (size_t)(i+1)*DIM*DIM, teb + (size_t)j*DIM, xbf, supbf, NN);
    else
      k_gemm_gate2<0><<<(NN+63)/64,256,0,stream>>>(hbf, stL,
          bng_h+(size_t)i*DIM, bnb_h+(size_t)i*DIM,
          Wt + (size_t)(6+j)*DIM*DIM, Wt + (size_t)(12+j)*DIM*DIM,
          Wt, teb + (size_t)j*DIM, xbf, supbf, NN);
  }

  // --- output layer (fp32 accumulate) ---
  k_gemm_out<<<(NN+7)/8,256,0,stream>>>(xbf, w_out, buf20, NN);
  k_spmm_out<<<NN/8,256,0,stream>>>(buf20, sedge, offs, (float*)hbf, 6*NN);
  float* bufO = (float*)hbf;   // NN*OUTC fp32 = 4 MB <= 12.8 MB
  k_bn_stats_out<<<512,256,0,stream>>>(bufO, ostat8, 98);
  k_reduce<<<512,256,0,stream>>>(bufO, ostat8, bng_o, bnb_o, verts, maskw, racc8, 98);
  k_final<<<1,64,0,stream>>>(racc8, maskb, out);
}

// Round 14
// 915.513 us; speedup vs baseline: 1.1161x; 1.0831x over previous
//
#include <hip/hip_runtime.h>
#include <hip/hip_fp16.h>

#define NN 50000
#define EE 800000
#define DIM 128
#define OUTC 20
#define LL 7
#define LE (LL*EE)
#define LN (LL*NN)
#define BN_EPS 1e-5f
#define LSTRIDE 136     // bf16 elems per LDS row
#define NREP 64         // BN stat replicas
#define NBUK 196        // coarse buckets of 256 dsts per layer
#define GMS  200        // padded Gm stride
#define NBLK 200        // edge-blocks per layer (EE/NBLK = 4000)
#define CH   4000
#define SCN  (LL*NBUK*NBLK)   // 274400 scan entries

typedef __attribute__((ext_vector_type(8))) short short8;
typedef __attribute__((ext_vector_type(4))) float f32x4;

static __device__ __forceinline__ float sigm(float z){ return 1.0f/(1.0f+expf(-z)); }
static __device__ __forceinline__ unsigned short f2bf(float f){
  unsigned int u = __float_as_uint(f);
  u += 0x7FFF + ((u>>16)&1);            // RNE
  return (unsigned short)(u>>16);
}
static __device__ __forceinline__ float bf2f(unsigned short s){
  return __uint_as_float(((unsigned int)s)<<16);
}

// ======== preprocessing: counting sort, all atomics in LDS, pure streaming ========

__global__ __launch_bounds__(256) void k_bh(const int* __restrict__ ei,
    int* __restrict__ Gm){
  int l = blockIdx.x / NBLK, b = blockIdx.x - l*NBLK;
  int t = threadIdx.x;
  __shared__ int h[NBUK];
  if (t<NBUK) h[t]=0;
  __syncthreads();
  const int* dsts = ei + (size_t)(2*l+1)*EE + b*CH;
  for (int k=t; k<CH; k+=256) atomicAdd(&h[__builtin_nontemporal_load(dsts+k)>>8], 1);
  __syncthreads();
  int* g = Gm + (size_t)(l*NBLK+b)*GMS;
  if (t<NBUK) g[t]=h[t];
}

__global__ __launch_bounds__(256) void k_scan1p(const int* __restrict__ Gm,
    int* __restrict__ part, int* __restrict__ bsums){
  __shared__ int s[256];
  int t = threadIdx.x;
  int base = blockIdx.x*4096 + t*16;
  int v[16]; int sum = 0;
  #pragma unroll
  for (int i=0;i<16;i++){
    int idx = base+i; int val = 0;
    if (idx < SCN){
      int l = idx/(NBUK*NBLK);
      int r = idx - l*(NBUK*NBLK);
      int buk = r/NBLK, b = r - buk*NBLK;
      val = Gm[(size_t)(l*NBLK+b)*GMS + buk];
    }
    v[i]=val; sum+=val;
  }
  s[t]=sum; __syncthreads();
  for (int off=1; off<256; off<<=1){
    int x = (t>=off)? s[t-off] : 0;
    __syncthreads(); s[t]+=x; __syncthreads();
  }
  if (t==255) bsums[blockIdx.x] = s[255];
  int run = s[t]-sum;
  #pragma unroll
  for (int i=0;i<16;i++){ if (base+i<SCN) part[base+i]=run; run += v[i]; }
}

__global__ __launch_bounds__(1024) void k_scan2(int* bsums, int nb){
  __shared__ int s[1024];
  int t=threadIdx.x;
  int v = (t<nb)? bsums[t]:0;
  s[t]=v; __syncthreads();
  for (int off=1; off<1024; off<<=1){
    int x=(t>=off)? s[t-off]:0; __syncthreads(); s[t]+=x; __syncthreads();
  }
  if (t<nb) bsums[t] = s[t]-v;
}

__global__ void k_scan3(int* __restrict__ S, const int* __restrict__ bsums){
  int gid = blockIdx.x*256+threadIdx.x;
  if (gid < SCN) S[gid] += bsums[gid>>12];
  if (gid==0) S[SCN]=LE;
}

// P3: LDS counting-sort by bucket with FINAL payload stored at placement
__global__ __launch_bounds__(256) void k_bscatter(const int* __restrict__ ei,
    const float* __restrict__ ew, const int* __restrict__ S,
    unsigned int* __restrict__ btmpP, unsigned char* __restrict__ btmpD){
  int l = blockIdx.x / NBLK, b = blockIdx.x - l*NBLK;
  int t = threadIdx.x;
  __shared__ int cnt[NBUK], bstart[NBUK], cur[NBUK], runb[NBUK];
  __shared__ int ps[256];
  __shared__ unsigned int  ebP[CH];     // 16 KB: src16|halfw16
  __shared__ unsigned short ebM[CH];    // 8 KB:  dlow8|buk8
  if (t<NBUK) cnt[t]=0;
  __syncthreads();
  const int* srcs = ei + (size_t)(2*l)*EE + b*CH;
  const int* dsts = ei + (size_t)(2*l+1)*EE + b*CH;
  const float* wsrc = ew + (size_t)l*EE + b*CH;
  for (int k=t;k<CH;k+=256) atomicAdd(&cnt[dsts[k]>>8],1);
  __syncthreads();
  int v = (t<NBUK)? cnt[t]:0;
  ps[t]=v; __syncthreads();
  for (int o=1;o<256;o<<=1){ int x=(t>=o)?ps[t-o]:0; __syncthreads(); ps[t]+=x; __syncthreads(); }
  if (t<NBUK){ bstart[t]=ps[t]-v; cur[t]=ps[t]-v; runb[t] = S[(size_t)(l*NBUK+t)*NBLK + b]; }
  __syncthreads();
  for (int k=t;k<CH;k+=256){
    int dst = dsts[k];
    int src = srcs[k];
    float w = wsrc[k];
    int buk = dst>>8;
    int pos = atomicAdd(&cur[buk],1);
    unsigned short hw = __half_as_ushort(__float2half(w));
    ebP[pos] = (unsigned)src | ((unsigned)hw<<16);
    ebM[pos] = (unsigned short)((dst&255) | (buk<<8));
  }
  __syncthreads();
  for (int k=t;k<CH;k+=256){
    unsigned short m = ebM[k];
    int buk = m>>8;
    int gp = runb[buk] + (k - bstart[buk]);
    btmpP[gp] = ebP[k];
    btmpD[gp] = (unsigned char)(m&255);
  }
}

// P4: per-bucket (256 dsts) count+scan from 1B dst array, direct scatter
__global__ __launch_bounds__(256) void k_fsort(const unsigned int* __restrict__ btmpP,
    const unsigned char* __restrict__ btmpD, const int* __restrict__ S,
    unsigned int* __restrict__ sedge, int* __restrict__ offs){
  int lbuk = blockIdx.x;
  int l = lbuk/NBUK, bl = lbuk - l*NBUK;
  int t = threadIdx.x;
  int base = S[(size_t)lbuk*NBLK];
  int end  = S[(size_t)(lbuk+1)*NBLK];
  int nE = end - base;
  __shared__ int cnt[256], sc[256];
  cnt[t]=0;
  __syncthreads();
  for (int k=t; k<nE; k+=256) atomicAdd(&cnt[btmpD[base+k]], 1);
  __syncthreads();
  int c = cnt[t];
  sc[t]=c;
  __syncthreads();
  for (int o=1;o<256;o<<=1){
    int v = (t>=o)? sc[t-o]:0;
    __syncthreads();
    sc[t]+=v;
    __syncthreads();
  }
  {
    int excl = sc[t]-c;
    int node = bl*256+t;
    if (node<NN) offs[(size_t)l*NN+node] = base + excl;
    cnt[t] = base + excl;
  }
  if (lbuk==0 && t==255) offs[LN]=LE;
  __syncthreads();
  for (int k=t; k<nE; k+=256){
    int d = btmpD[base+k];
    int r = atomicAdd(&cnt[d],1);
    sedge[r] = btmpP[base+k];
  }
}

// ---- transpose + bf16-convert all 18 hidden weight matrices: Wt[m][n][k] ----
__global__ __launch_bounds__(256) void k_prep_w(const float* __restrict__ wh,
    const float* __restrict__ tewl, const float* __restrict__ tewc,
    unsigned short* __restrict__ Wt){
  int gid = blockIdx.x*256+threadIdx.x;
  int m = gid>>14; int idx = gid&16383;
  int n = idx>>7, k = idx&127;
  const float* src = (m<6)? wh + (size_t)m*16384
                   : (m<12)? tewl + (size_t)(m-6)*16384
                   : tewc + (size_t)(m-12)*16384;
  Wt[gid] = f2bf(src[k*128+n]);
}

// -------- MFMA GEMM layer 0 (32-row tiles): gather emb, write xbf, compute sup --------
__global__ __launch_bounds__(256) void k_gemm_sup_emb(const int* __restrict__ verts,
    const float* __restrict__ emb, const unsigned short* __restrict__ Wt,
    unsigned short* __restrict__ Y, unsigned short* __restrict__ xout, int M){
  __shared__ unsigned short Xs[32*LSTRIDE];
  int tid = threadIdx.x;
  int row0 = blockIdx.x*32;
  #pragma unroll
  for (int it=0; it<2; it++){
    int idx = tid + it*256;
    int r = idx>>4, k8 = idx&15;
    short8 w = short8(0);
    if (row0+r < M){
      int v = verts[row0+r];
      const float4* p = (const float4*)emb + (size_t)v*32 + k8*2;
      float4 v0 = p[0], v1 = p[1];
      w[0]=(short)f2bf(v0.x); w[1]=(short)f2bf(v0.y); w[2]=(short)f2bf(v0.z); w[3]=(short)f2bf(v0.w);
      w[4]=(short)f2bf(v1.x); w[5]=(short)f2bf(v1.y); w[6]=(short)f2bf(v1.z); w[7]=(short)f2bf(v1.w);
      *(short8*)(xout + (size_t)(row0+r)*128 + k8*8) = w;
    }
    *(short8*)&Xs[r*LSTRIDE + k8*8] = w;
  }
  __syncthreads();
  int w = tid>>6, lane = tid&63, m = lane&15, q = lane>>4;
  int rw = (w&1)*16, cw = (w>>1)*64;
  f32x4 acc[4];
  #pragma unroll
  for (int nt=0;nt<4;nt++){ acc[nt][0]=0.f; acc[nt][1]=0.f; acc[nt][2]=0.f; acc[nt][3]=0.f; }
  #pragma unroll
  for (int kc=0; kc<4; kc++){
    short8 a = *(const short8*)&Xs[(rw+m)*LSTRIDE + kc*32 + 8*q];
    #pragma unroll
    for (int nt=0; nt<4; nt++){
      short8 b = *(const short8*)&Wt[(size_t)(cw+nt*16+m)*128 + kc*32 + 8*q];
      acc[nt] = __builtin_amdgcn_mfma_f32_16x16x32_bf16(a, b, acc[nt], 0,0,0);
    }
  }
  #pragma unroll
  for (int nt=0; nt<4; nt++){
    #pragma unroll
    for (int i=0;i<4;i++){
      int rr = row0 + rw + 4*q + i;
      if (rr<M) Y[(size_t)rr*128 + cw + nt*16 + m] = f2bf(acc[nt][i]);
    }
  }
}

// ------- fused gate (32-row tiles, front-loaded global reads): BN+ReLU; dual MFMA; gate; [+ next sup] -------
template<int FUSE>
__global__ __launch_bounds__(256) void k_gemm_gate2(const unsigned short* __restrict__ H,
    const float* __restrict__ stL,            // NREP replicas [rep][sum128|sq128]
    const float* __restrict__ gamma, const float* __restrict__ beta,
    const unsigned short* __restrict__ Wl, const unsigned short* __restrict__ Wc,
    const unsigned short* __restrict__ Wn, const float* __restrict__ teb,
    unsigned short* __restrict__ x, unsigned short* __restrict__ supY, int M){
  __shared__ unsigned short XsX[32*LSTRIDE];
  __shared__ unsigned short XsH[32*LSTRIDE];
  __shared__ float sSc[128], sOff[128];
  int tid = threadIdx.x;
  int row0 = blockIdx.x*32;
  // front-load ALL global reads before any barrier
  short8 xv[2], hv[2];
  #pragma unroll
  for (int it=0; it<2; it++){
    int idx = tid + it*256;
    int r = idx>>4, k8 = idx&15;
    xv[it] = short8(0); hv[it] = short8(0);
    if (row0+r < M){
      xv[it] = *(const short8*)(x + (size_t)(row0+r)*128 + k8*8);
      hv[it] = *(const short8*)(H + (size_t)(row0+r)*128 + k8*8);
    }
  }
  if (tid<128){
    float s=0.f, sq=0.f;
    #pragma unroll 8
    for (int g=0; g<NREP; g++){ s += stL[g*256+tid]; sq += stL[g*256+128+tid]; }
    float mean = s*(1.0f/NN);
    float var = sq*(1.0f/NN) - mean*mean;
    float sc = rsqrtf(var+BN_EPS)*gamma[tid];
    sSc[tid]=sc; sOff[tid]=beta[tid]-mean*sc;
  }
  #pragma unroll
  for (int it=0; it<2; it++){
    int idx = tid + it*256;
    int r = idx>>4, k8 = idx&15;
    *(short8*)&XsX[r*LSTRIDE + k8*8] = xv[it];
  }
  __syncthreads();
  #pragma unroll
  for (int it=0; it<2; it++){
    int idx = tid + it*256;
    int r = idx>>4, k8 = idx&15;
    int k = k8*8;
    short8 w;
    #pragma unroll
    for (int j=0;j<8;j++){
      float o = bf2f((unsigned short)hv[it][j]);
      float hn = fmaxf(fmaf(o, sSc[k+j], sOff[k+j]), 0.f);
      w[j] = (short)f2bf(hn);
    }
    *(short8*)&XsH[r*LSTRIDE + k8*8] = w;
  }
  __syncthreads();
  int w = tid>>6, lane = tid&63, m = lane&15, q = lane>>4;
  int rw = (w&1)*16, cw = (w>>1)*64;
  f32x4 acc[4];
  #pragma unroll
  for (int nt=0;nt<4;nt++){ acc[nt][0]=0.f; acc[nt][1]=0.f; acc[nt][2]=0.f; acc[nt][3]=0.f; }
  #pragma unroll
  for (int kc=0; kc<4; kc++){
    short8 a = *(const short8*)&XsX[(rw+m)*LSTRIDE + kc*32 + 8*q];
    #pragma unroll
    for (int nt=0; nt<4; nt++){
      short8 b = *(const short8*)&Wl[(size_t)(cw+nt*16+m)*128 + kc*32 + 8*q];
      acc[nt] = __builtin_amdgcn_mfma_f32_16x16x32_bf16(a, b, acc[nt], 0,0,0);
    }
  }
  #pragma unroll
  for (int kc=0; kc<4; kc++){
    short8 a = *(const short8*)&XsH[(rw+m)*LSTRIDE + kc*32 + 8*q];
    #pragma unroll
    for (int nt=0; nt<4; nt++){
      short8 b = *(const short8*)&Wc[(size_t)(cw+nt*16+m)*128 + kc*32 + 8*q];
      acc[nt] = __builtin_amdgcn_mfma_f32_16x16x32_bf16(a, b, acc[nt], 0,0,0);
    }
  }
  // gate epilogue: write xn into XsH (each cell owned by one thread), XsX too if FUSE
  #pragma unroll
  for (int nt=0; nt<4; nt++){
    int col = cw + nt*16 + m;
    float bias = teb[col];
    #pragma unroll
    for (int i=0;i<4;i++){
      int lr = rw + 4*q + i;
      float hvv = bf2f(XsH[lr*LSTRIDE + col]);
      float xo = bf2f(XsX[lr*LSTRIDE + col]);
      float g = sigm(acc[nt][i] + bias);
      unsigned short xnb = f2bf(g*hvv + (1.f-g)*xo);
      XsH[lr*LSTRIDE + col] = xnb;
      if (FUSE) XsX[lr*LSTRIDE + col] = xnb;
    }
  }
  __syncthreads();
  // coalesced short8 writeback of x_new
  #pragma unroll
  for (int it=0; it<2; it++){
    int idx = tid + it*256;
    int r = idx>>4, k8 = idx&15;
    if (row0+r < M)
      *(short8*)(x + (size_t)(row0+r)*128 + k8*8) = *(short8*)&XsH[r*LSTRIDE + k8*8];
  }
  if (FUSE){
    #pragma unroll
    for (int nt=0;nt<4;nt++){ acc[nt][0]=0.f; acc[nt][1]=0.f; acc[nt][2]=0.f; acc[nt][3]=0.f; }
    #pragma unroll
    for (int kc=0; kc<4; kc++){
      short8 a = *(const short8*)&XsX[(rw+m)*LSTRIDE + kc*32 + 8*q];
      #pragma unroll
      for (int nt=0; nt<4; nt++){
        short8 b = *(const short8*)&Wn[(size_t)(cw+nt*16+m)*128 + kc*32 + 8*q];
        acc[nt] = __builtin_amdgcn_mfma_f32_16x16x32_bf16(a, b, acc[nt], 0,0,0);
      }
    }
    #pragma unroll
    for (int nt=0; nt<4; nt++){
      #pragma unroll
      for (int i=0;i<4;i++){
        int rr = row0 + rw + 4*q + i;
        if (rr<M) supY[(size_t)rr*128 + cw + nt*16 + m] = f2bf(acc[nt][i]);
      }
    }
  }
}

// ---------------- Y[M,20] = bf16 X[M,128] @ W[128,20] (fp32 acc) ----------------
__global__ __launch_bounds__(256) void k_gemm_out(const unsigned short* __restrict__ X,
    const float* __restrict__ W, float* __restrict__ Y, int M){
  __shared__ float Ws[DIM*OUTC];
  __shared__ float Xs2[8*DIM];
  int tid=threadIdx.x;
  for (int i=tid;i<DIM*OUTC;i+=256) Ws[i]=W[i];
  int row0=blockIdx.x*8;
  if (tid<128){
    int r = tid>>4, k8 = tid&15;
    short8 v = short8(0);
    if (row0+r<M) v = *(const short8*)(X + (size_t)(row0+r)*128 + k8*8);
    #pragma unroll
    for (int j=0;j<8;j++) Xs2[r*DIM+k8*8+j] = bf2f((unsigned short)v[j]);
  }
  __syncthreads();
  int c = tid&31, rl=tid>>5;
  if (c<OUTC && row0+rl<M){
    float acc=0.f;
    #pragma unroll 8
    for (int k=0;k<DIM;k++) acc += Xs2[rl*DIM+k]*Ws[k*OUTC+c];
    Y[(size_t)(row0+rl)*OUTC+c]=acc;
  }
}

// -------- SpMM gather (contiguous per-node edges, 4-deep unroll) + fused BN stats --------
__global__ __launch_bounds__(256) void k_spmm128(const unsigned short* __restrict__ sup,
    const unsigned int* __restrict__ sedge, const int* __restrict__ offs,
    unsigned short* __restrict__ h, int lbase, float* __restrict__ stL){
  int nl = threadIdx.x>>5;
  int node = blockIdx.x*8 + nl;
  int fq = threadIdx.x & 31;
  int p = offs[lbase+node], end = offs[lbase+node+1];
  float4 a0 = make_float4(0.f,0.f,0.f,0.f), a1 = a0, a2 = a0, a3 = a0;
  for (; p+3<end; p+=4){
    unsigned int e0 = __builtin_nontemporal_load(sedge+p);
    unsigned int e1 = __builtin_nontemporal_load(sedge+p+1);
    unsigned int e2 = __builtin_nontemporal_load(sedge+p+2);
    unsigned int e3 = __builtin_nontemporal_load(sedge+p+3);
    ushort4 s0 = *(const ushort4*)(sup + (size_t)(e0&0xFFFFu)*128 + fq*4);
    ushort4 s1 = *(const ushort4*)(sup + (size_t)(e1&0xFFFFu)*128 + fq*4);
    ushort4 s2 = *(const ushort4*)(sup + (size_t)(e2&0xFFFFu)*128 + fq*4);
    ushort4 s3 = *(const ushort4*)(sup + (size_t)(e3&0xFFFFu)*128 + fq*4);
    float w0 = __half2float(__ushort_as_half((unsigned short)(e0>>16)));
    float w1 = __half2float(__ushort_as_half((unsigned short)(e1>>16)));
    float w2 = __half2float(__ushort_as_half((unsigned short)(e2>>16)));
    float w3 = __half2float(__ushort_as_half((unsigned short)(e3>>16)));
    a0.x += w0*bf2f(s0.x); a0.y += w0*bf2f(s0.y); a0.z += w0*bf2f(s0.z); a0.w += w0*bf2f(s0.w);
    a1.x += w1*bf2f(s1.x); a1.y += w1*bf2f(s1.y); a1.z += w1*bf2f(s1.z); a1.w += w1*bf2f(s1.w);
    a2.x += w2*bf2f(s2.x); a2.y += w2*bf2f(s2.y); a2.z += w2*bf2f(s2.z); a2.w += w2*bf2f(s2.w);
    a3.x += w3*bf2f(s3.x); a3.y += w3*bf2f(s3.y); a3.z += w3*bf2f(s3.z); a3.w += w3*bf2f(s3.w);
  }
  for (; p<end; p++){
    unsigned int e0 = __builtin_nontemporal_load(sedge+p);
    float w0 = __half2float(__ushort_as_half((unsigned short)(e0>>16)));
    ushort4 s0 = *(const ushort4*)(sup + (size_t)(e0&0xFFFFu)*128 + fq*4);
    a0.x += w0*bf2f(s0.x); a0.y += w0*bf2f(s0.y); a0.z += w0*bf2f(s0.z); a0.w += w0*bf2f(s0.w);
  }
  a0.x+=a1.x+a2.x+a3.x; a0.y+=a1.y+a2.y+a3.y;
  a0.z+=a1.z+a2.z+a3.z; a0.w+=a1.w+a2.w+a3.w;
  ushort4 ov;
  ov.x=f2bf(a0.x); ov.y=f2bf(a0.y); ov.z=f2bf(a0.z); ov.w=f2bf(a0.w);
  *(ushort4*)(h + (size_t)node*128 + fq*4) = ov;
  __shared__ float sP[8][132], sQ[8][132];
  int f0 = fq*4;
  sP[nl][f0+0]=a0.x; sP[nl][f0+1]=a0.y; sP[nl][f0+2]=a0.z; sP[nl][f0+3]=a0.w;
  sQ[nl][f0+0]=a0.x*a0.x; sQ[nl][f0+1]=a0.y*a0.y; sQ[nl][f0+2]=a0.z*a0.z; sQ[nl][f0+3]=a0.w*a0.w;
  __syncthreads();
  if (threadIdx.x < 128){
    int f = threadIdx.x;
    float s=0.f, sq=0.f;
    #pragma unroll
    for (int n=0;n<8;n++){ s += sP[n][f]; sq += sQ[n][f]; }
    float* base = stL + (blockIdx.x & (NREP-1))*256;
    atomicAdd(&base[f], s); atomicAdd(&base[128+f], sq);
  }
}

__global__ __launch_bounds__(256) void k_spmm_out(const float* __restrict__ sup,
    const unsigned int* __restrict__ sedge, const int* __restrict__ offs,
    float* __restrict__ h, int lbase){
  int node = blockIdx.x*8 + (threadIdx.x>>5);
  int c = threadIdx.x & 31;
  int p = offs[lbase+node], end = offs[lbase+node+1];
  float acc=0.f;
  for (; p<end; p++){
    unsigned int e = __builtin_nontemporal_load(sedge+p);
    float w = __half2float(__ushort_as_half((unsigned short)(e>>16)));
    if (c<OUTC) acc += w*sup[(size_t)(e&0xFFFFu)*OUTC+c];
  }
  if (c<OUTC) h[(size_t)node*OUTC+c]=acc;
}

// ---------------- output-layer BN stats (8-way replicated) ----------------
__global__ __launch_bounds__(256) void k_bn_stats_out(const float* __restrict__ h,
    float* __restrict__ st8, int rpb){
  int f = threadIdx.x % 32;
  int g = threadIdx.x / 32;
  float s=0.f, ss=0.f;
  int r0 = blockIdx.x*rpb;
  int r1 = min(NN, r0+rpb);
  if (f < OUTC){
    for (int r=r0+g; r<r1; r+=8){ float v = h[(size_t)r*OUTC+f]; s+=v; ss+=v*v; }
  }
  __shared__ float sh[256], sh2[256];
  sh[threadIdx.x]=s; sh2[threadIdx.x]=ss; __syncthreads();
  if (threadIdx.x < 32){
    #pragma unroll
    for (int i=1;i<8;i++){ s+=sh[threadIdx.x+i*32]; ss+=sh2[threadIdx.x+i*32]; }
    if (f<OUTC){
      float* base = st8 + (blockIdx.x&7)*64;
      atomicAdd(&base[f], s); atomicAdd(&base[32+f], ss);
    }
  }
}

// ---------- fused: BN-normalize+ReLU inline + masked reduce (8-way replicated) ----------
__global__ __launch_bounds__(256) void k_reduce(const float* __restrict__ xf,
    const float* __restrict__ st8, const float* __restrict__ gamma,
    const float* __restrict__ beta, const int* __restrict__ verts,
    const float* __restrict__ mw, float* __restrict__ acc8, int rpb){
  int c = threadIdx.x & 31, g = threadIdx.x >> 5;
  float scn=0.f, offc=0.f;
  if (c<OUTC){
    float s=0.f, sq=0.f;
    #pragma unroll
    for (int i=0;i<8;i++){ s += st8[i*64+c]; sq += st8[i*64+32+c]; }
    const float invN = 1.0f/NN;
    float m = s*invN;
    float var = sq*invN - m*m;
    scn = rsqrtf(var+BN_EPS)*gamma[c];
    offc = beta[c] - m*scn;
  }
  int r0 = blockIdx.x*rpb;
  int r1 = min(NN, r0+rpb);
  float s=0.f;
  for (int r=r0+g; r<r1; r+=8){
    float m = mw[verts[r]];
    if (c<OUTC){
      float v = fmaxf(fmaf(xf[(size_t)r*OUTC+c], scn, offc), 0.f);
      s += m * v;
    }
  }
  __shared__ float sh[256];
  sh[threadIdx.x]=s; __syncthreads();
  if (threadIdx.x<32){
    #pragma unroll
    for (int i=1;i<8;i++) s += sh[threadIdx.x + i*32];
    if (c<OUTC) atomicAdd(&acc8[(blockIdx.x&7)*32 + c], s);
  }
}

__global__ void k_final(const float* __restrict__ acc8, const float* __restrict__ mb,
                        float* __restrict__ out){
  int c=threadIdx.x;
  if (c<OUTC){
    float s=0.f;
    #pragma unroll
    for (int g=0; g<8; g++) s += acc8[g*32+c];
    out[c] = sigm(s+mb[c]);
  }
}

// ---------------- host ----------------
extern "C" void kernel_launch(void* const* d_in, const int* in_sizes, int n_in,
                              void* d_out, int out_size, void* d_ws, size_t ws_size,
                              hipStream_t stream){
  const int*   verts = (const int*)d_in[0];
  const int*   ei    = (const int*)d_in[1];
  const float* ew    = (const float*)d_in[2];
  const float* emb   = (const float*)d_in[3];
  const float* wh    = (const float*)d_in[4];
  const float* w_out = (const float*)d_in[6];
  const float* bng_h = (const float*)d_in[8];
  const float* bnb_h = (const float*)d_in[9];
  const float* bng_o = (const float*)d_in[10];
  const float* bnb_o = (const float*)d_in[11];
  const float* tewl  = (const float*)d_in[12];
  const float* tewc  = (const float*)d_in[13];
  const float* teb   = (const float*)d_in[14];
  const float* maskw = (const float*)d_in[15];
  const float* maskb = (const float*)d_in[16];
  float* out = (float*)d_out;

  char* ws = (char*)d_ws;
  size_t off=0;
  auto alloc=[&](size_t bytes)->char*{ char* p = ws+off; off += (bytes+255)&~(size_t)255; return p; };
  unsigned int* sedge = (unsigned int*)alloc(sizeof(int)*LE);   // 22.4 MB
  int*   offs   = (int*)  alloc(sizeof(int)*(LN+1));            // 1.4 MB
  int*   Gm     = (int*)  alloc(sizeof(int)*LL*NBLK*GMS);       // 1.1 MB
  int*   S      = (int*)  alloc(sizeof(int)*(SCN+1));           // 1.1 MB
  int*   bsums  = (int*)  alloc(sizeof(int)*1024);
  unsigned short* xbf   = (unsigned short*)alloc(sizeof(short)*NN*DIM); // 12.8 MB
  unsigned short* supbf = (unsigned short*)alloc(sizeof(short)*NN*DIM); // 12.8 MB
  unsigned short* hbf   = (unsigned short*)alloc(sizeof(short)*NN*DIM); // 12.8 MB
  float* buf20  = (float*)alloc(sizeof(float)*NN*OUTC);         // 4 MB
  unsigned short* Wt = (unsigned short*)alloc(sizeof(short)*18*DIM*DIM);
  const int STATSZ = 6*NREP*256 + 8*64 + 8*32;
  float* stats  = (float*)alloc(sizeof(float)*STATSZ);
  float* ostat8 = stats + 6*NREP*256;  // [8][64]
  float* racc8  = ostat8 + 8*64;       // [8][32]
  unsigned int*  btmpP = (unsigned int*)xbf;
  unsigned char* btmpD = (unsigned char*)hbf;

  // --- preprocessing: 4-pass LDS-atomic counting sort ---
  hipMemsetAsync(stats, 0, sizeof(float)*STATSZ, stream);
  k_prep_w<<<1152,256,0,stream>>>(wh, tewl, tewc, Wt);
  k_bh<<<LL*NBLK,256,0,stream>>>(ei, Gm);
  int nsb = (SCN+4095)/4096;  // 68
  k_scan1p<<<nsb,256,0,stream>>>(Gm, S, bsums);
  k_scan2<<<1,1024,0,stream>>>(bsums, nsb);
  k_scan3<<<(SCN+255)/256,256,0,stream>>>(S, bsums);
  k_bscatter<<<LL*NBLK,256,0,stream>>>(ei, ew, S, btmpP, btmpD);
  k_fsort<<<LL*NBUK,256,0,stream>>>(btmpP, btmpD, S, sedge, offs);

  // --- 6 hidden layers; sup for layer i+1 computed inside gate2 of layer i ---
  k_gemm_sup_emb<<<(NN+31)/32,256,0,stream>>>(verts, emb, Wt, supbf, xbf, NN);
  for (int i=0;i<6;i++){
    int j = (i==0)?5:(i-1);
    float* stL = stats + i*NREP*256;
    k_spmm128<<<NN/8,256,0,stream>>>(supbf, sedge, offs, hbf, i*NN, stL);
    if (i<5)
      k_gemm_gate2<1><<<(NN+31)/32,256,0,stream>>>(hbf, stL,
          bng_h+(size_t)i*DIM, bnb_h+(size_t)i*DIM,
          Wt + (size_t)(6+j)*DIM*DIM, Wt + (size_t)(12+j)*DIM*DIM,
          Wt + (size_t)(i+1)*DIM*DIM, teb + (size_t)j*DIM, xbf, supbf, NN);
    else
      k_gemm_gate2<0><<<(NN+31)/32,256,0,stream>>>(hbf, stL,
          bng_h+(size_t)i*DIM, bnb_h+(size_t)i*DIM,
          Wt + (size_t)(6+j)*DIM*DIM, Wt + (size_t)(12+j)*DIM*DIM,
          Wt, teb + (size_t)j*DIM, xbf, supbf, NN);
  }

  // --- output layer (fp32 accumulate) ---
  k_gemm_out<<<(NN+7)/8,256,0,stream>>>(xbf, w_out, buf20, NN);
  k_spmm_out<<<NN/8,256,0,stream>>>(buf20, sedge, offs, (float*)hbf, 6*NN);
  float* bufO = (float*)hbf;
  k_bn_stats_out<<<512,256,0,stream>>>(bufO, ostat8, 98);
  k_reduce<<<512,256,0,stream>>>(bufO, ostat8, bng_o, bnb_o, verts, maskw, racc8, 98);
  k_final<<<1,64,0,stream>>>(racc8, maskb, out);
}